// Round 1
// baseline (337.810 us; speedup 1.0000x reference)
//
#include <hip/hip_runtime.h>

// Problem constants (derived at launch from in_sizes, but sized for):
//   N=4096 nodes, D=512 d_model, H=4 heads.
//
// Math reduction (see analysis): softmax row-score cancels; attn = adj/deg,
// head-independent. out = relu( rownorm(adj) @ (nodes @ (W_node @ Kbar) + b_node @ Kbar) )
// with Kbar = mean_h K[h].

#define TS 64   // GEMM tile (M and N)
#define KS 16   // GEMM K-step

// Kbar[d,f] = (1/H) * sum_h K[h,d,f]
__global__ void kbar_kernel(const float* __restrict__ K, float* __restrict__ Kbar,
                            int DD, int H, float invH) {
    int idx = blockIdx.x * 256 + threadIdx.x;
    if (idx < DD) {
        float s = 0.f;
        for (int h = 0; h < H; ++h) s += K[(size_t)h * DD + idx];
        Kbar[idx] = s * invH;
    }
}

// bias2[f] = sum_d b[d] * Kbar[d*D+f]
__global__ void bias2_kernel(const float* __restrict__ b, const float* __restrict__ Kbar,
                             float* __restrict__ bias2, int D) {
    int f = blockIdx.x * 256 + threadIdx.x;
    if (f < D) {
        float s = 0.f;
        for (int d = 0; d < D; ++d) s += b[d] * Kbar[(size_t)d * D + f];
        bias2[f] = s;
    }
}

// C[M x N] = A[M x K] @ B[K x N] (+ bias[N] if non-null). fp32, 64x64 tile,
// 16x16 threads, 4x4 microtile, K-step 16.
__global__ __launch_bounds__(256) void gemm_kernel(
        const float* __restrict__ A, const float* __restrict__ B,
        const float* __restrict__ bias, float* __restrict__ C,
        int M, int N, int Kd) {
    __shared__ float As[KS][TS];   // As[k][m]
    __shared__ float Bs[KS][TS];   // Bs[k][n]
    const int tid = threadIdx.x;
    const int tx = tid % 16, ty = tid / 16;
    const int row0 = blockIdx.y * TS, col0 = blockIdx.x * TS;

    float acc[4][4] = {};

    for (int k0 = 0; k0 < Kd; k0 += KS) {
        // A tile: 64 rows x 16 k. 256 threads x float4 = 1024 elems.
        {
            int r  = tid / 4;            // 0..63
            int c4 = (tid % 4) * 4;      // 0,4,8,12
            float4 v = *reinterpret_cast<const float4*>(
                &A[(size_t)(row0 + r) * Kd + k0 + c4]);
            As[c4 + 0][r] = v.x;
            As[c4 + 1][r] = v.y;
            As[c4 + 2][r] = v.z;
            As[c4 + 3][r] = v.w;
        }
        // B tile: 16 k x 64 cols.
        {
            int r  = tid / 16;           // 0..15
            int c4 = (tid % 16) * 4;     // 0..60
            float4 v = *reinterpret_cast<const float4*>(
                &B[(size_t)(k0 + r) * N + col0 + c4]);
            *reinterpret_cast<float4*>(&Bs[r][c4]) = v;
        }
        __syncthreads();

#pragma unroll
        for (int kk = 0; kk < KS; ++kk) {
            float4 av = *reinterpret_cast<const float4*>(&As[kk][ty * 4]);
            float4 bv = *reinterpret_cast<const float4*>(&Bs[kk][tx * 4]);
            float a[4] = {av.x, av.y, av.z, av.w};
            float b[4] = {bv.x, bv.y, bv.z, bv.w};
#pragma unroll
            for (int i = 0; i < 4; ++i)
#pragma unroll
                for (int j = 0; j < 4; ++j)
                    acc[i][j] += a[i] * b[j];
        }
        __syncthreads();
    }

#pragma unroll
    for (int i = 0; i < 4; ++i) {
        int r = row0 + ty * 4 + i;
#pragma unroll
        for (int j = 0; j < 4; ++j) {
            int c = col0 + tx * 4 + j;
            float v = acc[i][j];
            if (bias) v += bias[c];
            C[(size_t)r * N + c] = v;
        }
    }
}

// out[i,f] = relu( (1/deg_i) * sum_{j: adj[i,j]>0.5} g[j,f] )
// One block per row i; 256 threads; D assumed == 512 (2 features/thread).
__global__ __launch_bounds__(256) void aggregate_kernel(
        const float* __restrict__ adj, const float* __restrict__ g,
        float* __restrict__ out, int N, int D) {
    const int row = blockIdx.x;
    const int tid = threadIdx.x;
    __shared__ int lst[256];
    __shared__ int cnt;

    float acc0 = 0.f, acc1 = 0.f;
    int deg = 0;
    const float* arow = adj + (size_t)row * N;

    for (int base = 0; base < N; base += 256) {
        if (tid == 0) cnt = 0;
        __syncthreads();
        float a = arow[base + tid];
        if (a > 0.5f) {
            int p = atomicAdd(&cnt, 1);
            lst[p] = base + tid;
        }
        __syncthreads();
        int c = cnt;
        for (int k = 0; k < c; ++k) {
            const float* grow = g + (size_t)lst[k] * D;
            acc0 += grow[tid];
            acc1 += grow[tid + 256];
        }
        deg += c;
        __syncthreads();
    }

    float inv = (deg > 0) ? 1.0f / (float)deg : 0.f;
    acc0 *= inv;
    acc1 *= inv;
    out[(size_t)row * D + tid]       = acc0 > 0.f ? acc0 : 0.f;
    out[(size_t)row * D + tid + 256] = acc1 > 0.f ? acc1 : 0.f;
}

extern "C" void kernel_launch(void* const* d_in, const int* in_sizes, int n_in,
                              void* d_out, int out_size, void* d_ws, size_t ws_size,
                              hipStream_t stream) {
    const float* nodes  = (const float*)d_in[0];
    const float* adj    = (const float*)d_in[1];
    const float* W_node = (const float*)d_in[2];
    const float* b_node = (const float*)d_in[3];
    const float* K      = (const float*)d_in[4];
    // d_in[5] A_self, d_in[6] A_neigh: dead code (softmax row-constant cancels)
    // d_in[7] num_heads scalar: derived from sizes instead.

    const int D = in_sizes[3];               // 512
    const int N = in_sizes[0] / D;           // 4096
    const int H = in_sizes[4] / (D * D);     // 4
    const int DD = D * D;

    float* out = (float*)d_out;

    // Workspace layout (floats): Kbar[DD] | Mmat[DD] | bias2[D] | g[N*D]
    float* ws    = (float*)d_ws;
    float* Kbar  = ws;
    float* Mmat  = ws + DD;
    float* bias2 = ws + 2 * (size_t)DD;
    float* g     = bias2 + D;  // offset 2*DD + D floats (16B aligned for D%4==0)

    // 1. Kbar = mean_h K[h]
    kbar_kernel<<<(DD + 255) / 256, 256, 0, stream>>>(K, Kbar, DD, H, 1.0f / (float)H);

    // 2. bias2 = b_node @ Kbar
    bias2_kernel<<<(D + 255) / 256, 256, 0, stream>>>(b_node, Kbar, bias2, D);

    // 3. Mmat = W_node @ Kbar   (D x D x D)
    {
        dim3 grid(D / TS, D / TS);
        gemm_kernel<<<grid, 256, 0, stream>>>(W_node, Kbar, nullptr, Mmat, D, D, D);
    }

    // 4. g = nodes @ Mmat + bias2   (N x D x D)
    {
        dim3 grid(D / TS, N / TS);
        gemm_kernel<<<grid, 256, 0, stream>>>(nodes, Mmat, bias2, g, N, D, D);
    }

    // 5. out = relu(rownorm(adj) @ g)
    aggregate_kernel<<<N, 256, 0, stream>>>(adj, g, out, N, D);
}

// Round 2
// 233.770 us; speedup vs baseline: 1.4450x; 1.4450x over previous
//
#include <hip/hip_runtime.h>

// N=4096 nodes, D=512 d_model, H=4 heads.
//
// Math reduction: softmax row-score cancels; attn = adj/deg, head-independent.
// out = relu( rownorm(adj) @ (nodes @ (W_node @ Kbar) + b_node @ Kbar) ),
// Kbar = mean_h K[h]. A_self/A_neigh/LeakyReLU are dead code.

#define TS 64   // GEMM tile (M and N)
#define KS 16   // GEMM K-step

// Kbar[d,f] = (1/H) * sum_h K[h,d,f]
__global__ void kbar_kernel(const float* __restrict__ K, float* __restrict__ Kbar,
                            int DD, int H, float invH) {
    int idx = blockIdx.x * 256 + threadIdx.x;
    if (idx < DD) {
        float s = 0.f;
        for (int h = 0; h < H; ++h) s += K[(size_t)h * DD + idx];
        Kbar[idx] = s * invH;
    }
}

// bias2[f] += sum_{d in chunk} b[d] * Kbar[d,f]  — f coalesced, d split across
// blockIdx.y, partials merged via atomicAdd (bias2 pre-zeroed by memsetAsync).
// R1 post-mortem: old version was 2 blocks of strided column walks = 123 us.
__global__ void bias2_kernel(const float* __restrict__ b, const float* __restrict__ Kbar,
                             float* __restrict__ bias2, int D, int dchunk) {
    int f = blockIdx.x * 256 + threadIdx.x;
    if (f >= D) return;
    int d0 = blockIdx.y * dchunk;
    float s = 0.f;
    for (int d = d0; d < d0 + dchunk; ++d)
        s += b[d] * Kbar[(size_t)d * D + f];
    atomicAdd(&bias2[f], s);
}

// C[M x N] = A[M x K] @ B[K x N] (+ bias[N] if non-null). fp32, 64x64 tile,
// 16x16 threads, 4x4 microtile, K-step 16.
__global__ __launch_bounds__(256) void gemm_kernel(
        const float* __restrict__ A, const float* __restrict__ B,
        const float* __restrict__ bias, float* __restrict__ C,
        int M, int N, int Kd) {
    __shared__ float As[KS][TS];   // As[k][m]
    __shared__ float Bs[KS][TS];   // Bs[k][n]
    const int tid = threadIdx.x;
    const int tx = tid % 16, ty = tid / 16;
    const int row0 = blockIdx.y * TS, col0 = blockIdx.x * TS;

    float acc[4][4] = {};

    for (int k0 = 0; k0 < Kd; k0 += KS) {
        {
            int r  = tid / 4;            // 0..63
            int c4 = (tid % 4) * 4;      // 0,4,8,12
            float4 v = *reinterpret_cast<const float4*>(
                &A[(size_t)(row0 + r) * Kd + k0 + c4]);
            As[c4 + 0][r] = v.x;
            As[c4 + 1][r] = v.y;
            As[c4 + 2][r] = v.z;
            As[c4 + 3][r] = v.w;
        }
        {
            int r  = tid / 16;           // 0..15
            int c4 = (tid % 16) * 4;     // 0..60
            float4 v = *reinterpret_cast<const float4*>(
                &B[(size_t)(k0 + r) * N + col0 + c4]);
            *reinterpret_cast<float4*>(&Bs[r][c4]) = v;
        }
        __syncthreads();

#pragma unroll
        for (int kk = 0; kk < KS; ++kk) {
            float4 av = *reinterpret_cast<const float4*>(&As[kk][ty * 4]);
            float4 bv = *reinterpret_cast<const float4*>(&Bs[kk][tx * 4]);
            float a[4] = {av.x, av.y, av.z, av.w};
            float b[4] = {bv.x, bv.y, bv.z, bv.w};
#pragma unroll
            for (int i = 0; i < 4; ++i)
#pragma unroll
                for (int j = 0; j < 4; ++j)
                    acc[i][j] += a[i] * b[j];
        }
        __syncthreads();
    }

#pragma unroll
    for (int i = 0; i < 4; ++i) {
        int r = row0 + ty * 4 + i;
#pragma unroll
        for (int j = 0; j < 4; ++j) {
            int c = col0 + tx * 4 + j;
            float v = acc[i][j];
            if (bias) v += bias[c];
            C[(size_t)r * N + c] = v;
        }
    }
}

// out[i,f] = relu( (1/deg_i) * sum_{j: adj[i,j]>0.5} g[j,f] )
// One block per row i; 256 threads; D == 512 (2 features/thread).
__global__ __launch_bounds__(256) void aggregate_kernel(
        const float* __restrict__ adj, const float* __restrict__ g,
        float* __restrict__ out, int N, int D) {
    const int row = blockIdx.x;
    const int tid = threadIdx.x;
    __shared__ int lst[256];
    __shared__ int cnt;

    float acc0 = 0.f, acc1 = 0.f;
    int deg = 0;
    const float* arow = adj + (size_t)row * N;

    for (int base = 0; base < N; base += 256) {
        if (tid == 0) cnt = 0;
        __syncthreads();
        float a = arow[base + tid];
        if (a > 0.5f) {
            int p = atomicAdd(&cnt, 1);
            lst[p] = base + tid;
        }
        __syncthreads();
        int c = cnt;
        for (int k = 0; k < c; ++k) {
            const float* grow = g + (size_t)lst[k] * D;
            acc0 += grow[tid];
            acc1 += grow[tid + 256];
        }
        deg += c;
        __syncthreads();
    }

    float inv = (deg > 0) ? 1.0f / (float)deg : 0.f;
    acc0 *= inv;
    acc1 *= inv;
    out[(size_t)row * D + tid]       = acc0 > 0.f ? acc0 : 0.f;
    out[(size_t)row * D + tid + 256] = acc1 > 0.f ? acc1 : 0.f;
}

extern "C" void kernel_launch(void* const* d_in, const int* in_sizes, int n_in,
                              void* d_out, int out_size, void* d_ws, size_t ws_size,
                              hipStream_t stream) {
    const float* nodes  = (const float*)d_in[0];
    const float* adj    = (const float*)d_in[1];
    const float* W_node = (const float*)d_in[2];
    const float* b_node = (const float*)d_in[3];
    const float* K      = (const float*)d_in[4];
    // d_in[5] A_self, d_in[6] A_neigh: dead (softmax row-constant cancels).

    const int D = in_sizes[3];               // 512
    const int N = in_sizes[0] / D;           // 4096
    const int H = in_sizes[4] / (D * D);     // 4
    const int DD = D * D;

    float* out = (float*)d_out;

    // Workspace layout (floats): Kbar[DD] | Mmat[DD] | bias2[D] | g[N*D]
    float* ws    = (float*)d_ws;
    float* Kbar  = ws;
    float* Mmat  = ws + DD;
    float* bias2 = ws + 2 * (size_t)DD;
    float* g     = bias2 + D;

    // 1. Kbar = mean_h K[h]
    kbar_kernel<<<(DD + 255) / 256, 256, 0, stream>>>(K, Kbar, DD, H, 1.0f / (float)H);

    // 2. bias2 = b_node @ Kbar  (zero accumulator, then 2D-split reduction)
    hipMemsetAsync(bias2, 0, D * sizeof(float), stream);
    {
        const int DSPLIT = 32;
        dim3 grid((D + 255) / 256, DSPLIT);
        bias2_kernel<<<grid, 256, 0, stream>>>(b_node, Kbar, bias2, D, D / DSPLIT);
    }

    // 3. Mmat = W_node @ Kbar   (D x D x D)
    {
        dim3 grid(D / TS, D / TS);
        gemm_kernel<<<grid, 256, 0, stream>>>(W_node, Kbar, nullptr, Mmat, D, D, D);
    }

    // 4. g = nodes @ Mmat + bias2   (N x D x D)
    {
        dim3 grid(D / TS, N / TS);
        gemm_kernel<<<grid, 256, 0, stream>>>(nodes, Mmat, bias2, g, N, D, D);
    }

    // 5. out = relu(rownorm(adj) @ g)
    aggregate_kernel<<<N, 256, 0, stream>>>(adj, g, out, N, D);
}

// Round 3
// 161.972 us; speedup vs baseline: 2.0856x; 1.4433x over previous
//
#include <hip/hip_runtime.h>
#include <hip/hip_bf16.h>

// N=4096 nodes, D=512 d_model, H=4 heads.
//
// Math reduction: softmax row-score cancels (s[h,i] constant over softmax axis);
// exp(NEG)==0 in fp32 and self-loops guarantee deg>=1, so attn = adj/deg,
// head-independent. A_self/A_neigh/LeakyReLU are dead code.
//   out = relu( rownorm(adj) @ (nodes @ Mmat + b_node @ Kbar) ),
//   Mmat = W_node @ Kbar,  Kbar = mean_h K[h].
// Pipeline (bf16 MFMA for both GEMMs, bf16 g for the gather):
//   KbarT_bf16 = transpose(mean_h K)        [D,D] k-major
//   W_bf16     = cast(W_node)               [D,K] k-major (natural)
//   MmatT_bf16 = KbarT @ W^T  (MFMA A@Bt)   [f][d]
//   nodes_bf16 = cast(nodes)
//   g_bf16     = nodes @ MmatT^T + bias2    (MFMA A@Bt)
//   out        = relu(rownorm(adj) @ g)     (list-build + unrolled gather)

typedef short  short8 __attribute__((ext_vector_type(8)));
typedef float  f32x4  __attribute__((ext_vector_type(4)));

__device__ inline unsigned short f2bf(float f) {
    union { float f; unsigned int u; } v; v.f = f;
    unsigned int u = v.u;
    u += 0x7fffu + ((u >> 16) & 1u);       // round-nearest-even
    return (unsigned short)(u >> 16);
}

// KbarT[f*D+d] = bf16( (1/H) * sum_h K[h,d,f] ).  Writes coalesced in d;
// strided K reads are L2-absorbed (K is 4 MB).
__global__ void kbarT_kernel(const float* __restrict__ K, unsigned short* __restrict__ KbarT,
                             int D, int H, float invH) {
    int idx = blockIdx.x * 256 + threadIdx.x;
    int DD = D * D;
    if (idx >= DD) return;
    int f = idx / D, d = idx - f * D;
    float s = 0.f;
    for (int h = 0; h < H; ++h) s += K[(size_t)h * DD + d * D + f];
    KbarT[idx] = f2bf(s * invH);
}

// elementwise fp32 -> bf16, 8 elems/thread
__global__ void cast_bf16_kernel(const float* __restrict__ in, unsigned short* __restrict__ out,
                                 int n8) {
    int idx = blockIdx.x * 256 + threadIdx.x;
    if (idx >= n8) return;
    const float4* p = reinterpret_cast<const float4*>(in) + (size_t)idx * 2;
    float4 a = p[0], b = p[1];
    short8 v;
    v[0] = (short)f2bf(a.x); v[1] = (short)f2bf(a.y);
    v[2] = (short)f2bf(a.z); v[3] = (short)f2bf(a.w);
    v[4] = (short)f2bf(b.x); v[5] = (short)f2bf(b.y);
    v[6] = (short)f2bf(b.z); v[7] = (short)f2bf(b.w);
    *reinterpret_cast<short8*>(out + (size_t)idx * 8) = v;
}

// bias2[f] = sum_d b[d] * Kbar[d,f], one wave per f reading KbarT row (contiguous).
// D assumed 512 (lane*8 covers it exactly).
__global__ __launch_bounds__(256) void bias2_kernel(
        const float* __restrict__ b, const unsigned short* __restrict__ KbarT,
        float* __restrict__ bias2, int D) {
    int wid  = (blockIdx.x * 256 + threadIdx.x) >> 6;   // global wave id == f
    int lane = threadIdx.x & 63;
    if (wid >= D) return;
    const unsigned short* kr = KbarT + (size_t)wid * D + lane * 8;
    const float* br = b + lane * 8;
    float s = 0.f;
#pragma unroll
    for (int j = 0; j < 8; ++j) {
        union { unsigned int i; float f; } v; v.i = ((unsigned int)kr[j]) << 16;
        s += br[j] * v.f;
    }
#pragma unroll
    for (int off = 32; off; off >>= 1) s += __shfl_down(s, off, 64);
    if (lane == 0) bias2[wid] = s;
}

// C[m][n] = sum_k A[m][k]*Bt[n][k] (+bias[n]), bf16 in, bf16 out, fp32 acc.
// 64x64 tile, BK=32, 256 threads = 4 waves in 2x2, each wave 32x32 via
// 2x2 of 16x16x32 MFMA. m92-verified structure (A and Bt both k-major).
__global__ __launch_bounds__(256) void gemm_bf16_kernel(
        const unsigned short* __restrict__ A,   // [M][K]
        const unsigned short* __restrict__ Bt,  // [Nn][K]
        const float* __restrict__ bias,         // [Nn] or null
        unsigned short* __restrict__ C,         // [M][Nn]
        int M, int Nn, int K) {
    __shared__ unsigned short As[64][32];
    __shared__ unsigned short Bs[64][32];
    const int tid  = threadIdx.x;
    const int lane = tid & 63;
    const int wave = tid >> 6;
    const int wy = wave >> 1, wx = wave & 1;
    const int row0 = blockIdx.y * 64, col0 = blockIdx.x * 64;
    const int l15 = lane & 15, quad = lane >> 4;

    const int ldr = tid >> 2;         // staging row 0..63
    const int ldk = (tid & 3) * 8;    // staging k offset

    f32x4 acc[2][2] = {};

    for (int k0 = 0; k0 < K; k0 += 32) {
        short8 av = *reinterpret_cast<const short8*>(&A [(size_t)(row0 + ldr) * K + k0 + ldk]);
        short8 bv = *reinterpret_cast<const short8*>(&Bt[(size_t)(col0 + ldr) * K + k0 + ldk]);
        __syncthreads();   // previous iter's LDS reads done before overwrite
        *reinterpret_cast<short8*>(&As[ldr][ldk]) = av;
        *reinterpret_cast<short8*>(&Bs[ldr][ldk]) = bv;
        __syncthreads();
        // A-frag layout: A[m=lane&15][k=quad*8+j]; B-frag mirrors with n=lane&15.
        short8 a0 = *reinterpret_cast<const short8*>(&As[wy * 32 +      l15][quad * 8]);
        short8 a1 = *reinterpret_cast<const short8*>(&As[wy * 32 + 16 + l15][quad * 8]);
        short8 b0 = *reinterpret_cast<const short8*>(&Bs[wx * 32 +      l15][quad * 8]);
        short8 b1 = *reinterpret_cast<const short8*>(&Bs[wx * 32 + 16 + l15][quad * 8]);
        acc[0][0] = __builtin_amdgcn_mfma_f32_16x16x32_bf16(a0, b0, acc[0][0], 0, 0, 0);
        acc[0][1] = __builtin_amdgcn_mfma_f32_16x16x32_bf16(a0, b1, acc[0][1], 0, 0, 0);
        acc[1][0] = __builtin_amdgcn_mfma_f32_16x16x32_bf16(a1, b0, acc[1][0], 0, 0, 0);
        acc[1][1] = __builtin_amdgcn_mfma_f32_16x16x32_bf16(a1, b1, acc[1][1], 0, 0, 0);
    }

    // C/D layout: col = lane&15, row = (lane>>4)*4 + reg  [m89-verified]
#pragma unroll
    for (int mi = 0; mi < 2; ++mi)
#pragma unroll
        for (int ni = 0; ni < 2; ++ni) {
            int col = col0 + wx * 32 + ni * 16 + l15;
            float bv = bias ? bias[col] : 0.f;
#pragma unroll
            for (int r = 0; r < 4; ++r) {
                int row = row0 + wy * 32 + mi * 16 + quad * 4 + r;
                C[(size_t)row * Nn + col] = f2bf(acc[mi][ni][r] + bv);
            }
        }
}

// out[i,:] = relu( (1/deg_i) * sum_{j: adj[i,j]=1} g[j,:] )
// One block per row. Phase 1: one-pass neighbor-list build (single barrier).
// Phase 2: unrolled-by-8 gather of bf16 g rows (8 loads in flight/thread).
// Assumes N%1024==0, D==512.
__global__ __launch_bounds__(256) void aggregate_kernel(
        const float* __restrict__ adj, const unsigned short* __restrict__ g,
        float* __restrict__ out, int N, int D) {
    const int row = blockIdx.x;
    const int tid = threadIdx.x;
    __shared__ int lst[1024];
    __shared__ int cnt;
    if (tid == 0) cnt = 0;
    __syncthreads();

    const float* arow = adj + (size_t)row * N;
    const int nper = N >> 8;            // elems per thread (16 @ N=4096)
    const int base = tid * nper;
    const float4* ap = reinterpret_cast<const float4*>(arow + base);
    for (int c = 0; c < (nper >> 2); ++c) {
        float4 a = ap[c];
        int b4 = base + c * 4;
        if (a.x > 0.5f) { int p = atomicAdd(&cnt, 1); if (p < 1024) lst[p] = b4;     }
        if (a.y > 0.5f) { int p = atomicAdd(&cnt, 1); if (p < 1024) lst[p] = b4 + 1; }
        if (a.z > 0.5f) { int p = atomicAdd(&cnt, 1); if (p < 1024) lst[p] = b4 + 2; }
        if (a.w > 0.5f) { int p = atomicAdd(&cnt, 1); if (p < 1024) lst[p] = b4 + 3; }
    }
    __syncthreads();
    int deg = cnt; if (deg > 1024) deg = 1024;

    const int col = tid * 2;            // D==512: 2 features/thread
    float acc0 = 0.f, acc1 = 0.f;
    int k = 0;
    for (; k + 8 <= deg; k += 8) {
        unsigned int u[8];
#pragma unroll
        for (int j = 0; j < 8; ++j)
            u[j] = *reinterpret_cast<const unsigned int*>(&g[(size_t)lst[k + j] * D + col]);
#pragma unroll
        for (int j = 0; j < 8; ++j) {
            union { unsigned int i; float f; } lo, hi;
            lo.i = u[j] << 16; hi.i = u[j] & 0xffff0000u;
            acc0 += lo.f; acc1 += hi.f;
        }
    }
    for (; k < deg; ++k) {
        unsigned int u = *reinterpret_cast<const unsigned int*>(&g[(size_t)lst[k] * D + col]);
        union { unsigned int i; float f; } lo, hi;
        lo.i = u << 16; hi.i = u & 0xffff0000u;
        acc0 += lo.f; acc1 += hi.f;
    }

    float inv = deg > 0 ? 1.f / (float)deg : 0.f;
    acc0 *= inv; acc1 *= inv;
    float2 o;
    o.x = acc0 > 0.f ? acc0 : 0.f;
    o.y = acc1 > 0.f ? acc1 : 0.f;
    *reinterpret_cast<float2*>(&out[(size_t)row * D + col]) = o;
}

extern "C" void kernel_launch(void* const* d_in, const int* in_sizes, int n_in,
                              void* d_out, int out_size, void* d_ws, size_t ws_size,
                              hipStream_t stream) {
    const float* nodes  = (const float*)d_in[0];
    const float* adj    = (const float*)d_in[1];
    const float* W_node = (const float*)d_in[2];
    const float* b_node = (const float*)d_in[3];
    const float* K      = (const float*)d_in[4];
    // d_in[5] A_self, d_in[6] A_neigh: dead (softmax row-constant cancels).

    const int D  = in_sizes[3];              // 512
    const int N  = in_sizes[0] / D;          // 4096
    const int H  = in_sizes[4] / (D * D);    // 4
    const int DD = D * D;

    float* out = (float*)d_out;

    // ws layout (bytes): KbarT[DD*2] W_bf16[DD*2] MmatT[DD*2] nodes_bf16[N*D*2]
    //                    g_bf16[N*D*2] bias2[D*4]   total ~9.5 MB
    char* ws = (char*)d_ws;
    unsigned short* KbarT    = (unsigned short*)(ws);
    unsigned short* W_bf16   = (unsigned short*)(ws + (size_t)DD * 2);
    unsigned short* MmatT    = (unsigned short*)(ws + (size_t)DD * 4);
    unsigned short* nodes_bf = (unsigned short*)(ws + (size_t)DD * 6);
    unsigned short* g_bf16   = (unsigned short*)(ws + (size_t)DD * 6 + (size_t)N * D * 2);
    float*          bias2    = (float*)        (ws + (size_t)DD * 6 + (size_t)N * D * 4);

    // 1. KbarT = transpose(mean_h K), bf16
    kbarT_kernel<<<(DD + 255) / 256, 256, 0, stream>>>(K, KbarT, D, H, 1.0f / (float)H);

    // 2. casts
    cast_bf16_kernel<<<(DD / 8 + 255) / 256, 256, 0, stream>>>(W_node, W_bf16, DD / 8);
    cast_bf16_kernel<<<(N * D / 8 + 255) / 256, 256, 0, stream>>>(nodes, nodes_bf, N * D / 8);

    // 3. bias2 = b_node @ Kbar   (wave-per-f reduction over KbarT rows)
    bias2_kernel<<<(D * 64 + 255) / 256, 256, 0, stream>>>(b_node, KbarT, bias2, D);

    // 4. MmatT[f][d] = sum_k KbarT[f][k] * W[d][k]   (MFMA, 64 blocks)
    {
        dim3 grid(D / 64, D / 64);
        gemm_bf16_kernel<<<grid, 256, 0, stream>>>(KbarT, W_bf16, nullptr, MmatT, D, D, D);
    }

    // 5. g[n][f] = sum_k nodes[n][k] * MmatT[f][k] + bias2[f]   (MFMA, 512 blocks)
    {
        dim3 grid(D / 64, N / 64);
        gemm_bf16_kernel<<<grid, 256, 0, stream>>>(nodes_bf, MmatT, bias2, g_bf16, N, D, D);
    }

    // 6. out = relu(rownorm(adj) @ g)
    aggregate_kernel<<<N, 256, 0, stream>>>(adj, g_bf16, out, N, D);
}

// Round 4
// 159.902 us; speedup vs baseline: 2.1126x; 1.0129x over previous
//
#include <hip/hip_runtime.h>

// N=4096 nodes, D=512 d_model, H=4 heads.
//
// Math reduction: softmax row-score s[h,i] is constant along the softmax axis
// so it cancels; exp(-1e10)==0 in fp32 and self-loops guarantee deg>=1, so
// attn = adj/deg, head-independent. A_self/A_neigh/LeakyReLU are dead code.
//   out = relu( rownorm(adj) @ (nodes @ Mmat + b_node @ Kbar) ),
//   Mmat = W_node @ Kbar,  Kbar = mean_h K[h].
// R4: 4 kernels total (launches are serialized on one stream, so fewer is
// faster): kbarT (LDS transpose) -> gemm1+bias2 fused -> gemm2 -> aggregate.
// GEMMs convert fp32 operands to bf16 in-register during LDS staging (no
// standalone cast kernels).

typedef short  short8 __attribute__((ext_vector_type(8)));
typedef float  f32x4  __attribute__((ext_vector_type(4)));

__device__ inline unsigned short f2bf(float f) {
    union { float f; unsigned int u; } v; v.f = f;
    unsigned int u = v.u;
    u += 0x7fffu + ((u >> 16) & 1u);       // round-nearest-even
    return (unsigned short)(u >> 16);
}

// KbarT[f][d] = bf16( (1/H) * sum_h K[h][d][f] ), via 64x64 LDS transpose tile.
// Reads coalesced (f inner), writes coalesced (d inner). Grid (D/64, D/64).
__global__ __launch_bounds__(256) void kbarT_kernel(
        const float* __restrict__ K, unsigned short* __restrict__ KbarT,
        int D, int H, float invH) {
    __shared__ float tile[64][65];         // [d][f], +1 pad for transposed read
    const int f0 = blockIdx.x * 64, d0 = blockIdx.y * 64;
    const int tid = threadIdx.x;
    const int c4 = (tid & 15) * 4;         // inner offset (f on load, d on store)
    const int DD = D * D;

    for (int rr = tid >> 4; rr < 64; rr += 16) {
        float sx = 0.f, sy = 0.f, sz = 0.f, sw = 0.f;
        for (int h = 0; h < H; ++h) {
            float4 v = *reinterpret_cast<const float4*>(
                &K[(size_t)h * DD + (size_t)(d0 + rr) * D + f0 + c4]);
            sx += v.x; sy += v.y; sz += v.z; sw += v.w;
        }
        tile[rr][c4 + 0] = sx * invH;
        tile[rr][c4 + 1] = sy * invH;
        tile[rr][c4 + 2] = sz * invH;
        tile[rr][c4 + 3] = sw * invH;
    }
    __syncthreads();
    for (int fr = tid >> 4; fr < 64; fr += 16) {
        ushort4 o;
        o.x = f2bf(tile[c4 + 0][fr]);
        o.y = f2bf(tile[c4 + 1][fr]);
        o.z = f2bf(tile[c4 + 2][fr]);
        o.w = f2bf(tile[c4 + 3][fr]);
        *reinterpret_cast<ushort4*>(&KbarT[(size_t)(f0 + fr) * D + d0 + c4]) = o;
    }
}

// Shared MFMA GEMM body: C[m][n] = sum_k A[m][k]*Bt[n][k] (+bias[n]),
// fp32 acc, bf16 out. CA/CB: operand is fp32 and converted during staging.
// 64x64 tile, BK=32, 4 waves in 2x2, each wave 2x2 of 16x16x32 MFMA.
template <bool CA, bool CB>
__device__ inline void gemm_body(const void* __restrict__ Ap,
                                 const void* __restrict__ Btp,
                                 const float* __restrict__ bias,
                                 unsigned short* __restrict__ C,
                                 int Nn, int K, int bx, int by) {
    __shared__ unsigned short As[64][32];
    __shared__ unsigned short Bs[64][32];
    const int tid  = threadIdx.x;
    const int lane = tid & 63;
    const int wave = tid >> 6;
    const int wy = wave >> 1, wx = wave & 1;
    const int row0 = by * 64, col0 = bx * 64;
    const int l15 = lane & 15, quad = lane >> 4;
    const int ldr = tid >> 2;          // staging row 0..63
    const int ldk = (tid & 3) * 8;     // staging k offset

    f32x4 acc[2][2] = {};

    for (int k0 = 0; k0 < K; k0 += 32) {
        short8 av, bv;
        if (CA) {
            const float* a = (const float*)Ap + (size_t)(row0 + ldr) * K + k0 + ldk;
            float4 x = *reinterpret_cast<const float4*>(a);
            float4 y = *reinterpret_cast<const float4*>(a + 4);
            av[0] = (short)f2bf(x.x); av[1] = (short)f2bf(x.y);
            av[2] = (short)f2bf(x.z); av[3] = (short)f2bf(x.w);
            av[4] = (short)f2bf(y.x); av[5] = (short)f2bf(y.y);
            av[6] = (short)f2bf(y.z); av[7] = (short)f2bf(y.w);
        } else {
            av = *reinterpret_cast<const short8*>(
                (const unsigned short*)Ap + (size_t)(row0 + ldr) * K + k0 + ldk);
        }
        if (CB) {
            const float* b = (const float*)Btp + (size_t)(col0 + ldr) * K + k0 + ldk;
            float4 x = *reinterpret_cast<const float4*>(b);
            float4 y = *reinterpret_cast<const float4*>(b + 4);
            bv[0] = (short)f2bf(x.x); bv[1] = (short)f2bf(x.y);
            bv[2] = (short)f2bf(x.z); bv[3] = (short)f2bf(x.w);
            bv[4] = (short)f2bf(y.x); bv[5] = (short)f2bf(y.y);
            bv[6] = (short)f2bf(y.z); bv[7] = (short)f2bf(y.w);
        } else {
            bv = *reinterpret_cast<const short8*>(
                (const unsigned short*)Btp + (size_t)(col0 + ldr) * K + k0 + ldk);
        }
        __syncthreads();   // previous iter's LDS reads done before overwrite
        *reinterpret_cast<short8*>(&As[ldr][ldk]) = av;
        *reinterpret_cast<short8*>(&Bs[ldr][ldk]) = bv;
        __syncthreads();
        short8 a0 = *reinterpret_cast<const short8*>(&As[wy * 32 +      l15][quad * 8]);
        short8 a1 = *reinterpret_cast<const short8*>(&As[wy * 32 + 16 + l15][quad * 8]);
        short8 b0 = *reinterpret_cast<const short8*>(&Bs[wx * 32 +      l15][quad * 8]);
        short8 b1 = *reinterpret_cast<const short8*>(&Bs[wx * 32 + 16 + l15][quad * 8]);
        acc[0][0] = __builtin_amdgcn_mfma_f32_16x16x32_bf16(a0, b0, acc[0][0], 0, 0, 0);
        acc[0][1] = __builtin_amdgcn_mfma_f32_16x16x32_bf16(a0, b1, acc[0][1], 0, 0, 0);
        acc[1][0] = __builtin_amdgcn_mfma_f32_16x16x32_bf16(a1, b0, acc[1][0], 0, 0, 0);
        acc[1][1] = __builtin_amdgcn_mfma_f32_16x16x32_bf16(a1, b1, acc[1][1], 0, 0, 0);
    }

    // C/D layout: col = lane&15, row = (lane>>4)*4 + reg  [m89-verified]
#pragma unroll
    for (int mi = 0; mi < 2; ++mi)
#pragma unroll
        for (int ni = 0; ni < 2; ++ni) {
            int col = col0 + wx * 32 + ni * 16 + l15;
            float bvl = bias ? bias[col] : 0.f;
#pragma unroll
            for (int r = 0; r < 4; ++r) {
                int row = row0 + wy * 32 + mi * 16 + quad * 4 + r;
                C[(size_t)row * Nn + col] = f2bf(acc[mi][ni][r] + bvl);
            }
        }
}

// GEMM1 + fused bias2. Blocks with by < gemmY: MmatT[f][d] = sum_k KbarT[f][k]*W[d][k].
// Blocks with by >= gemmY: bias2[f] = sum_d b[d]*Kbar[d][f], one wave per f
// reading a contiguous KbarT row (assumes D==512: lane*8 spans the row).
__global__ __launch_bounds__(256) void gemm1_kernel(
        const unsigned short* __restrict__ KbarT, const float* __restrict__ W,
        const float* __restrict__ b, unsigned short* __restrict__ MmatT,
        float* __restrict__ bias2, int D, int gemmY) {
    if ((int)blockIdx.y >= gemmY) {
        int e = ((int)blockIdx.y - gemmY) * gridDim.x + blockIdx.x;
        int wave = threadIdx.x >> 6, lane = threadIdx.x & 63;
        int f = e * 4 + wave;
        if (f >= D) return;
        const unsigned short* kr = KbarT + (size_t)f * D + lane * 8;
        const float* br = b + lane * 8;
        float s = 0.f;
#pragma unroll
        for (int j = 0; j < 8; ++j) {
            union { unsigned int i; float f; } v; v.i = ((unsigned int)kr[j]) << 16;
            s += br[j] * v.f;
        }
#pragma unroll
        for (int off = 32; off; off >>= 1) s += __shfl_down(s, off, 64);
        if (lane == 0) bias2[f] = s;
        return;
    }
    gemm_body<false, true>(KbarT, W, nullptr, MmatT, D, D, blockIdx.x, blockIdx.y);
}

// GEMM2: g[n][f] = sum_d nodes[n][d]*MmatT[f][d] + bias2[f]
__global__ __launch_bounds__(256) void gemm2_kernel(
        const float* __restrict__ nodes, const unsigned short* __restrict__ MmatT,
        const float* __restrict__ bias2, unsigned short* __restrict__ g,
        int D, int K) {
    gemm_body<true, false>(nodes, MmatT, bias2, g, D, K, blockIdx.x, blockIdx.y);
}

// out[i,:] = relu( (1/deg_i) * sum_{j: adj[i,j]=1} g[j,:] )
// One block per row. Phase 1: one-pass neighbor-list build (single barrier).
// Phase 2: unrolled-by-8 gather of bf16 g rows. Assumes N%1024==0, D==512.
__global__ __launch_bounds__(256) void aggregate_kernel(
        const float* __restrict__ adj, const unsigned short* __restrict__ g,
        float* __restrict__ out, int N, int D) {
    const int row = blockIdx.x;
    const int tid = threadIdx.x;
    __shared__ int lst[1024];
    __shared__ int cnt;
    if (tid == 0) cnt = 0;
    __syncthreads();

    const float* arow = adj + (size_t)row * N;
    const int nper = N >> 8;
    const int base = tid * nper;
    const float4* ap = reinterpret_cast<const float4*>(arow + base);
    for (int c = 0; c < (nper >> 2); ++c) {
        float4 a = ap[c];
        int b4 = base + c * 4;
        if (a.x > 0.5f) { int p = atomicAdd(&cnt, 1); if (p < 1024) lst[p] = b4;     }
        if (a.y > 0.5f) { int p = atomicAdd(&cnt, 1); if (p < 1024) lst[p] = b4 + 1; }
        if (a.z > 0.5f) { int p = atomicAdd(&cnt, 1); if (p < 1024) lst[p] = b4 + 2; }
        if (a.w > 0.5f) { int p = atomicAdd(&cnt, 1); if (p < 1024) lst[p] = b4 + 3; }
    }
    __syncthreads();
    int deg = cnt; if (deg > 1024) deg = 1024;

    const int col = tid * 2;
    float acc0 = 0.f, acc1 = 0.f;
    int k = 0;
    for (; k + 8 <= deg; k += 8) {
        unsigned int u[8];
#pragma unroll
        for (int j = 0; j < 8; ++j)
            u[j] = *reinterpret_cast<const unsigned int*>(&g[(size_t)lst[k + j] * D + col]);
#pragma unroll
        for (int j = 0; j < 8; ++j) {
            union { unsigned int i; float f; } lo, hi;
            lo.i = u[j] << 16; hi.i = u[j] & 0xffff0000u;
            acc0 += lo.f; acc1 += hi.f;
        }
    }
    for (; k < deg; ++k) {
        unsigned int u = *reinterpret_cast<const unsigned int*>(&g[(size_t)lst[k] * D + col]);
        union { unsigned int i; float f; } lo, hi;
        lo.i = u << 16; hi.i = u & 0xffff0000u;
        acc0 += lo.f; acc1 += hi.f;
    }

    float inv = deg > 0 ? 1.f / (float)deg : 0.f;
    acc0 *= inv; acc1 *= inv;
    float2 o;
    o.x = acc0 > 0.f ? acc0 : 0.f;
    o.y = acc1 > 0.f ? acc1 : 0.f;
    *reinterpret_cast<float2*>(&out[(size_t)row * D + col]) = o;
}

extern "C" void kernel_launch(void* const* d_in, const int* in_sizes, int n_in,
                              void* d_out, int out_size, void* d_ws, size_t ws_size,
                              hipStream_t stream) {
    const float* nodes  = (const float*)d_in[0];
    const float* adj    = (const float*)d_in[1];
    const float* W_node = (const float*)d_in[2];
    const float* b_node = (const float*)d_in[3];
    const float* K      = (const float*)d_in[4];
    // d_in[5] A_self, d_in[6] A_neigh: dead (softmax row-constant cancels).

    const int D  = in_sizes[3];              // 512
    const int N  = in_sizes[0] / D;          // 4096
    const int H  = in_sizes[4] / (D * D);    // 4
    const int DD = D * D;

    float* out = (float*)d_out;

    // ws layout (bytes): KbarT[DD*2] | MmatT[DD*2] | g[N*D*2] | bias2[D*4]
    char* ws = (char*)d_ws;
    unsigned short* KbarT  = (unsigned short*)(ws);
    unsigned short* MmatT  = (unsigned short*)(ws + (size_t)DD * 2);
    unsigned short* g_bf16 = (unsigned short*)(ws + (size_t)DD * 4);
    float*          bias2  = (float*)        (ws + (size_t)DD * 4 + (size_t)N * D * 2);

    // 1. KbarT = transpose(mean_h K), bf16, LDS-tile transpose
    {
        dim3 grid(D / 64, D / 64);
        kbarT_kernel<<<grid, 256, 0, stream>>>(K, KbarT, D, H, 1.0f / (float)H);
    }

    // 2. MmatT = (W @ Kbar)^T via MFMA, + bias2 = b_node @ Kbar in extra rows
    {
        int gx = D / 64, gemmY = D / 64;
        int biasRows = (D / 4 + gx - 1) / gx;    // wave-per-f, 4 f per block
        dim3 grid(gx, gemmY + biasRows);
        gemm1_kernel<<<grid, 256, 0, stream>>>(KbarT, W_node, b_node, MmatT, bias2, D, gemmY);
    }

    // 3. g = nodes @ Mmat + bias2 (MFMA, fp32 A staged+converted in-kernel)
    {
        dim3 grid(D / 64, N / 64);
        gemm2_kernel<<<grid, 256, 0, stream>>>(nodes, MmatT, bias2, g_bf16, D, D);
    }

    // 4. out = relu(rownorm(adj) @ g)
    aggregate_kernel<<<N, 256, 0, stream>>>(adj, g_bf16, out, N, D);
}